// Round 1
// baseline (679.218 us; speedup 1.0000x reference)
//
#include <hip/hip_runtime.h>
#include <math.h>

#define T_LEN 8192
#define NTRIALS 1024
#define KLEN 50
#define CH 32
#define NCH (T_LEN / CH)

// ---------------------------------------------------------------------------
// Kernel 1: basc[j] = bias + stim_conv_shifted[j]  (f64), plus scalar params.
// stim_conv[n] = sum_m k_stim[m]*stim[n-m], *dt, shifted right by one.
// ---------------------------------------------------------------------------
__global__ void prep_basc_kernel(const float* __restrict__ t,
                                 const float* __restrict__ stim,
                                 const float* __restrict__ bias,
                                 const float* __restrict__ k_stim,
                                 const float* __restrict__ hist_w,
                                 const float* __restrict__ hist_tau,
                                 double* __restrict__ dparams,
                                 double* __restrict__ basc) {
  int j = blockIdx.x * blockDim.x + threadIdx.x;
  if (j >= T_LEN) return;
  double dt = (double)t[1] - (double)t[0];
  if (j == 0) {
    dparams[0] = exp(-dt / (double)hist_tau[0]);  // decay0
    dparams[1] = exp(-dt / (double)hist_tau[1]);  // decay1
    dparams[2] = (double)hist_w[0];               // w0
    dparams[3] = (double)hist_w[1];               // w1
    dparams[4] = dt;
    basc[0] = (double)bias[0];                    // shifted conv -> 0 at j=0
    return;
  }
  int n = j - 1;
  int mmax = n < (KLEN - 1) ? n : (KLEN - 1);
  double acc = 0.0;
  for (int m = 0; m <= mmax; ++m)
    acc += (double)k_stim[m] * (double)stim[n - m];
  basc[j] = (double)bias[0] + dt * acc;
}

// ---------------------------------------------------------------------------
// Kernel 2: per-element spike threshold in loglam-space (fully parallel).
// spike  <=>  p > r  <=>  loglam > log(-log1p(-r)/dt)
// thr[j,i] = log(-log1p(-r)/dt) - basc[j]   so the scan compares hist > thr.
// r == 0 -> thr = -inf -> always spike (matches p > 0).
// ---------------------------------------------------------------------------
__global__ void prep_thr_kernel(const float* __restrict__ rnd,
                                const double* __restrict__ basc,
                                const double* __restrict__ dparams,
                                double* __restrict__ thr) {
  int idx = blockIdx.x * blockDim.x + threadIdx.x;  // exactly T_LEN*NTRIALS threads
  double dt = dparams[4];
  double r = (double)rnd[idx];
  double u = -log1p(-r);          // -log(1-r) >= 0, exact in f64 since r is f32
  thr[idx] = log(u / dt) - basc[idx >> 10];  // NTRIALS == 1024
}

// ---------------------------------------------------------------------------
// Kernel 3: the serial scan. One thread per trial (1024 threads, 16 blocks).
// Critical chain per step: add -> cmp -> select -> fma (all f64).
// Threshold loads are double-buffered 32 deep to hide HBM latency.
// ---------------------------------------------------------------------------
__global__ __launch_bounds__(64, 1) void glm_scan_kernel(
    const double* __restrict__ thr, const double* __restrict__ basc,
    const double* __restrict__ dparams, float* __restrict__ out) {
  const int i = blockIdx.x * 64 + threadIdx.x;
  const double d0 = dparams[0], d1 = dparams[1];
  const double w0 = dparams[2], w1 = dparams[3];
  double s0 = 0.0, s1 = 0.0;
  float* __restrict__ out_ll = out;
  float* __restrict__ out_mk = out + (size_t)T_LEN * NTRIALS;
  const double* __restrict__ p = thr + i;

  double bufA[CH], bufB[CH];
#pragma unroll
  for (int k = 0; k < CH; ++k) bufA[k] = p[(size_t)k * NTRIALS];

  for (int c = 0; c < NCH; c += 2) {
    const int j0 = c * CH;
    // issue loads for chunk c+1 (always exists: NCH even)
#pragma unroll
    for (int k = 0; k < CH; ++k) bufB[k] = p[(size_t)(j0 + CH + k) * NTRIALS];
    // compute chunk c
#pragma unroll
    for (int k = 0; k < CH; ++k) {
      const int j = j0 + k;
      double hist = s0 + s1;
      bool spk = hist > bufA[k];
      out_ll[(size_t)j * NTRIALS + i] = (float)(basc[j] + hist);
      out_mk[(size_t)j * NTRIALS + i] = spk ? 1.0f : 0.0f;
      s0 = fma(d0, s0, spk ? w0 : 0.0);
      s1 = fma(d1, s1, spk ? w1 : 0.0);
    }
    // issue loads for chunk c+2
    if (c + 2 < NCH) {
#pragma unroll
      for (int k = 0; k < CH; ++k) bufA[k] = p[(size_t)(j0 + 2 * CH + k) * NTRIALS];
    }
    // compute chunk c+1
#pragma unroll
    for (int k = 0; k < CH; ++k) {
      const int j = j0 + CH + k;
      double hist = s0 + s1;
      bool spk = hist > bufB[k];
      out_ll[(size_t)j * NTRIALS + i] = (float)(basc[j] + hist);
      out_mk[(size_t)j * NTRIALS + i] = spk ? 1.0f : 0.0f;
      s0 = fma(d0, s0, spk ? w0 : 0.0);
      s1 = fma(d1, s1, spk ? w1 : 0.0);
    }
  }
}

// Fallback if d_ws is too small to hold the f64 threshold matrix: compute the
// threshold inline (slower, still correct).
__global__ __launch_bounds__(64, 1) void glm_scan_inline_kernel(
    const float* __restrict__ rnd, const double* __restrict__ basc,
    const double* __restrict__ dparams, float* __restrict__ out) {
  const int i = blockIdx.x * 64 + threadIdx.x;
  const double d0 = dparams[0], d1 = dparams[1];
  const double w0 = dparams[2], w1 = dparams[3];
  const double dt = dparams[4];
  double s0 = 0.0, s1 = 0.0;
  float* __restrict__ out_ll = out;
  float* __restrict__ out_mk = out + (size_t)T_LEN * NTRIALS;
  for (int j = 0; j < T_LEN; ++j) {
    double r = (double)rnd[(size_t)j * NTRIALS + i];
    double th = log(-log1p(-r) / dt) - basc[j];
    double hist = s0 + s1;
    bool spk = hist > th;
    out_ll[(size_t)j * NTRIALS + i] = (float)(basc[j] + hist);
    out_mk[(size_t)j * NTRIALS + i] = spk ? 1.0f : 0.0f;
    s0 = fma(d0, s0, spk ? w0 : 0.0);
    s1 = fma(d1, s1, spk ? w1 : 0.0);
  }
}

extern "C" void kernel_launch(void* const* d_in, const int* in_sizes, int n_in,
                              void* d_out, int out_size, void* d_ws, size_t ws_size,
                              hipStream_t stream) {
  const float* t        = (const float*)d_in[0];
  const float* stim     = (const float*)d_in[1];
  const float* rnd      = (const float*)d_in[2];
  const float* bias     = (const float*)d_in[3];
  const float* k_stim   = (const float*)d_in[4];
  const float* hist_w   = (const float*)d_in[5];
  const float* hist_tau = (const float*)d_in[6];
  float* out = (float*)d_out;

  char* ws = (char*)d_ws;
  double* dparams = (double*)ws;                       // 64 B reserved
  double* basc    = (double*)(ws + 64);                // T_LEN * 8 B
  double* thr     = (double*)(ws + 64 + T_LEN * 8);    // T_LEN * NTRIALS * 8 B
  size_t need = 64 + (size_t)T_LEN * 8 + (size_t)T_LEN * NTRIALS * 8;

  prep_basc_kernel<<<(T_LEN + 255) / 256, 256, 0, stream>>>(
      t, stim, bias, k_stim, hist_w, hist_tau, dparams, basc);

  if (ws_size >= need) {
    prep_thr_kernel<<<(T_LEN * NTRIALS) / 256, 256, 0, stream>>>(rnd, basc, dparams, thr);
    glm_scan_kernel<<<NTRIALS / 64, 64, 0, stream>>>(thr, basc, dparams, out);
  } else {
    glm_scan_inline_kernel<<<NTRIALS / 64, 64, 0, stream>>>(rnd, basc, dparams, out);
  }
}

// Round 2
// 392.134 us; speedup vs baseline: 1.7321x; 1.7321x over previous
//
#include <hip/hip_runtime.h>
#include <math.h>

#define T_LEN 8192
#define NTRIALS 1024
#define TN ((size_t)T_LEN * NTRIALS)
#define KLEN 50
#define CH 32
#define NCH (T_LEN / CH)

// ---------------------------------------------------------------------------
// Kernel 1: basc[j] = bias + stim_conv_shifted[j] (f64), plus scalar params.
// ---------------------------------------------------------------------------
__global__ void prep_basc_kernel(const float* __restrict__ t,
                                 const float* __restrict__ stim,
                                 const float* __restrict__ bias,
                                 const float* __restrict__ k_stim,
                                 const float* __restrict__ hist_w,
                                 const float* __restrict__ hist_tau,
                                 double* __restrict__ dparams,
                                 double* __restrict__ basc) {
  int j = blockIdx.x * blockDim.x + threadIdx.x;
  if (j >= T_LEN) return;
  double dt = (double)t[1] - (double)t[0];
  if (j == 0) {
    dparams[0] = exp(-dt / (double)hist_tau[0]);  // decay0
    dparams[1] = exp(-dt / (double)hist_tau[1]);  // decay1
    dparams[2] = (double)hist_w[0];               // w0
    dparams[3] = (double)hist_w[1];               // w1
    dparams[4] = dt;
    basc[0] = (double)bias[0];                    // shifted conv -> 0 at j=0
    return;
  }
  int n = j - 1;
  int mmax = n < (KLEN - 1) ? n : (KLEN - 1);
  double acc = 0.0;
  for (int m = 0; m <= mmax; ++m)
    acc += (double)k_stim[m] * (double)stim[n - m];
  basc[j] = (double)bias[0] + dt * acc;
}

// ---------------------------------------------------------------------------
// Kernel 2: per-element spike threshold in loglam-space (fully parallel).
// spike <=> hist > thr,  thr = log(-log1p(-r)/dt) - basc[j]
// ---------------------------------------------------------------------------
__global__ void prep_thr_kernel(const float* __restrict__ rnd,
                                const double* __restrict__ basc,
                                const double* __restrict__ dparams,
                                double* __restrict__ thr) {
  size_t idx = (size_t)blockIdx.x * blockDim.x + threadIdx.x;
  double dt = dparams[4];
  double r = (double)rnd[idx];
  double u = -log1p(-r);
  thr[idx] = log(u / dt) - basc[idx >> 10];  // NTRIALS == 1024
}

// ---------------------------------------------------------------------------
// Kernel 3 (tier 1): the serial scan, loads + recurrence + ONE f64 store.
// No other memory ops on the serial path. Double-buffered 32-deep prefetch,
// pinned with sched_barrier so the compiler can't fold it.
// ---------------------------------------------------------------------------
__global__ __launch_bounds__(64, 1) void glm_scan_f64_kernel(
    const double* __restrict__ thr, const double* __restrict__ dparams,
    double* __restrict__ hist_out) {
  const int i = blockIdx.x * 64 + threadIdx.x;
  const double d0 = dparams[0], d1 = dparams[1];
  const double w0 = dparams[2], w1 = dparams[3];
  double s0 = 0.0, s1 = 0.0;
  const double* __restrict__ p = thr + i;
  double* __restrict__ q = hist_out + i;

  double bufA[CH], bufB[CH];
#pragma unroll
  for (int k = 0; k < CH; ++k) bufA[k] = p[(size_t)k * NTRIALS];
  __builtin_amdgcn_sched_barrier(0);

  for (int c = 0; c < NCH; c += 2) {
    const size_t j0 = (size_t)c * CH;
    // issue loads for chunk c+1
#pragma unroll
    for (int k = 0; k < CH; ++k) bufB[k] = p[(j0 + CH + k) * NTRIALS];
    __builtin_amdgcn_sched_barrier(0);
    // compute chunk c
#pragma unroll
    for (int k = 0; k < CH; ++k) {
      double hist = s0 + s1;
      bool spk = hist > bufA[k];
      q[(j0 + k) * NTRIALS] = hist;
      s0 = fma(d0, s0, spk ? w0 : 0.0);
      s1 = fma(d1, s1, spk ? w1 : 0.0);
    }
    __builtin_amdgcn_sched_barrier(0);
    // issue loads for chunk c+2
    if (c + 2 < NCH) {
#pragma unroll
      for (int k = 0; k < CH; ++k) bufA[k] = p[(j0 + 2 * CH + k) * NTRIALS];
    }
    __builtin_amdgcn_sched_barrier(0);
    // compute chunk c+1
#pragma unroll
    for (int k = 0; k < CH; ++k) {
      double hist = s0 + s1;
      bool spk = hist > bufB[k];
      q[(j0 + CH + k) * NTRIALS] = hist;
      s0 = fma(d0, s0, spk ? w0 : 0.0);
      s1 = fma(d1, s1, spk ? w1 : 0.0);
    }
    __builtin_amdgcn_sched_barrier(0);
  }
}

// Tier-1 fixup: out_ll = f32(basc + hist); mask recomputed in IDENTICAL f64
// compare as the scan used, so the spike decisions match bit-exactly.
__global__ void fixup_full_kernel(const double* __restrict__ hist,
                                  const double* __restrict__ thr,
                                  const double* __restrict__ basc,
                                  float* __restrict__ out) {
  size_t m = (size_t)blockIdx.x * blockDim.x + threadIdx.x;  // TN/2 threads
  size_t idx = m * 2;
  double2 h = *reinterpret_cast<const double2*>(hist + idx);
  double2 th = *reinterpret_cast<const double2*>(thr + idx);
  double b = basc[idx >> 10];  // pair never straddles a row (1024 even)
  float2 ll = make_float2((float)(b + h.x), (float)(b + h.y));
  float2 mk = make_float2(h.x > th.x ? 1.0f : 0.0f, h.y > th.y ? 1.0f : 0.0f);
  *reinterpret_cast<float2*>(out + idx) = ll;
  *reinterpret_cast<float2*>(out + TN + idx) = mk;
}

// ---------------------------------------------------------------------------
// Tier 2: scan writes f32 hist + mask directly to out (2 stores/step),
// fixup adds basc to the log_lam plane. Used if ws can't hold hist f64.
// ---------------------------------------------------------------------------
__global__ __launch_bounds__(64, 1) void glm_scan_t2_kernel(
    const double* __restrict__ thr, const double* __restrict__ dparams,
    float* __restrict__ out) {
  const int i = blockIdx.x * 64 + threadIdx.x;
  const double d0 = dparams[0], d1 = dparams[1];
  const double w0 = dparams[2], w1 = dparams[3];
  double s0 = 0.0, s1 = 0.0;
  float* __restrict__ out_ll = out;
  float* __restrict__ out_mk = out + TN;
  const double* __restrict__ p = thr + i;

  double bufA[CH], bufB[CH];
#pragma unroll
  for (int k = 0; k < CH; ++k) bufA[k] = p[(size_t)k * NTRIALS];
  __builtin_amdgcn_sched_barrier(0);

  for (int c = 0; c < NCH; c += 2) {
    const size_t j0 = (size_t)c * CH;
#pragma unroll
    for (int k = 0; k < CH; ++k) bufB[k] = p[(j0 + CH + k) * NTRIALS];
    __builtin_amdgcn_sched_barrier(0);
#pragma unroll
    for (int k = 0; k < CH; ++k) {
      double hist = s0 + s1;
      bool spk = hist > bufA[k];
      out_ll[(j0 + k) * NTRIALS + i] = (float)hist;
      out_mk[(j0 + k) * NTRIALS + i] = spk ? 1.0f : 0.0f;
      s0 = fma(d0, s0, spk ? w0 : 0.0);
      s1 = fma(d1, s1, spk ? w1 : 0.0);
    }
    __builtin_amdgcn_sched_barrier(0);
    if (c + 2 < NCH) {
#pragma unroll
      for (int k = 0; k < CH; ++k) bufA[k] = p[(j0 + 2 * CH + k) * NTRIALS];
    }
    __builtin_amdgcn_sched_barrier(0);
#pragma unroll
    for (int k = 0; k < CH; ++k) {
      double hist = s0 + s1;
      bool spk = hist > bufB[k];
      out_ll[(j0 + CH + k) * NTRIALS + i] = (float)hist;
      out_mk[(j0 + CH + k) * NTRIALS + i] = spk ? 1.0f : 0.0f;
      s0 = fma(d0, s0, spk ? w0 : 0.0);
      s1 = fma(d1, s1, spk ? w1 : 0.0);
    }
    __builtin_amdgcn_sched_barrier(0);
  }
}

__global__ void fixup_basc_kernel(const double* __restrict__ basc,
                                  float* __restrict__ out) {
  size_t idx = (size_t)blockIdx.x * blockDim.x + threadIdx.x;
  out[idx] = (float)((double)out[idx] + basc[idx >> 10]);
}

// Tier 3: fully inline fallback (slow, always correct).
__global__ __launch_bounds__(64, 1) void glm_scan_inline_kernel(
    const float* __restrict__ rnd, const double* __restrict__ basc,
    const double* __restrict__ dparams, float* __restrict__ out) {
  const int i = blockIdx.x * 64 + threadIdx.x;
  const double d0 = dparams[0], d1 = dparams[1];
  const double w0 = dparams[2], w1 = dparams[3];
  const double dt = dparams[4];
  double s0 = 0.0, s1 = 0.0;
  float* __restrict__ out_ll = out;
  float* __restrict__ out_mk = out + TN;
  for (int j = 0; j < T_LEN; ++j) {
    double r = (double)rnd[(size_t)j * NTRIALS + i];
    double th = log(-log1p(-r) / dt) - basc[j];
    double hist = s0 + s1;
    bool spk = hist > th;
    out_ll[(size_t)j * NTRIALS + i] = (float)(basc[j] + hist);
    out_mk[(size_t)j * NTRIALS + i] = spk ? 1.0f : 0.0f;
    s0 = fma(d0, s0, spk ? w0 : 0.0);
    s1 = fma(d1, s1, spk ? w1 : 0.0);
  }
}

extern "C" void kernel_launch(void* const* d_in, const int* in_sizes, int n_in,
                              void* d_out, int out_size, void* d_ws, size_t ws_size,
                              hipStream_t stream) {
  const float* t        = (const float*)d_in[0];
  const float* stim     = (const float*)d_in[1];
  const float* rnd      = (const float*)d_in[2];
  const float* bias     = (const float*)d_in[3];
  const float* k_stim   = (const float*)d_in[4];
  const float* hist_w   = (const float*)d_in[5];
  const float* hist_tau = (const float*)d_in[6];
  float* out = (float*)d_out;

  char* ws = (char*)d_ws;
  const size_t off_basc = 64;
  const size_t off_thr  = off_basc + (size_t)T_LEN * 8;
  const size_t off_hist = off_thr + TN * 8;
  const size_t need_t2  = off_hist;           // params + basc + thr
  const size_t need_t1  = off_hist + TN * 8;  // + f64 hist plane

  double* dparams = (double*)ws;
  double* basc    = (double*)(ws + off_basc);
  double* thr     = (double*)(ws + off_thr);
  double* hist    = (double*)(ws + off_hist);

  prep_basc_kernel<<<(T_LEN + 255) / 256, 256, 0, stream>>>(
      t, stim, bias, k_stim, hist_w, hist_tau, dparams, basc);

  if (ws_size >= need_t1) {
    prep_thr_kernel<<<(int)(TN / 256), 256, 0, stream>>>(rnd, basc, dparams, thr);
    glm_scan_f64_kernel<<<NTRIALS / 64, 64, 0, stream>>>(thr, dparams, hist);
    fixup_full_kernel<<<(int)(TN / 2 / 256), 256, 0, stream>>>(hist, thr, basc, out);
  } else if (ws_size >= need_t2) {
    prep_thr_kernel<<<(int)(TN / 256), 256, 0, stream>>>(rnd, basc, dparams, thr);
    glm_scan_t2_kernel<<<NTRIALS / 64, 64, 0, stream>>>(thr, dparams, out);
    fixup_basc_kernel<<<(int)(TN / 256), 256, 0, stream>>>(basc, out);
  } else {
    glm_scan_inline_kernel<<<NTRIALS / 64, 64, 0, stream>>>(rnd, basc, dparams, out);
  }
}